// Round 11
// baseline (1707.833 us; speedup 1.0000x reference)
//
#include <hip/hip_runtime.h>
#include <hip/hip_bf16.h>
#include <hip/hip_fp16.h>
#include <stdint.h>

#define NNODES 50000
#define NPAD   50048          // 391 * 128
#define DEG    16
#define DIN    963
#define K0PAD  992            // 31 * 32
#define DHID   256
#define SCALE  (1.0f / 1024.0f)
#define ISCALE 1024.0f

typedef __attribute__((ext_vector_type(4))) float    f32x4;
typedef __attribute__((ext_vector_type(8))) _Float16 f16x8;
typedef __attribute__((ext_vector_type(4))) _Float16 f16x4;

typedef const __attribute__((address_space(1))) void GV;
typedef __attribute__((address_space(3))) void LV;

__device__ __forceinline__ void gl2lds16(const void* g, void* l) {
    __builtin_amdgcn_global_load_lds((GV*)g, (LV*)l, 16, 0, 0);
}

// bijective XCD swizzle (m204)
__device__ __forceinline__ int xcd_swz(int bid, int nwg) {
    const int q = nwg >> 3, r_ = nwg & 7, xc = bid & 7;
    return (xc < r_ ? xc * (q + 1) : r_ * (q + 1) + (xc - r_) * q) + (bid >> 3);
}

#define PIPE_WAIT(n)  do { asm volatile("s_waitcnt vmcnt(" #n ")" ::: "memory"); } while (0)
#define SCHED_FENCE() __builtin_amdgcn_sched_barrier(0)

// ---------------- layer-0 dual GEMM, 3-buffer counted-vmcnt pipeline ----------------
// Grid 1-D 1564: wgid>>2 = row-tile, wgid&3 = col-block (siblings adjacent -> A L2-share).
// Per step each thread issues 4 gl2lds (2 A + 2 B); wait vmcnt(4) keeps next 2 tiles in flight.
__global__ __launch_bounds__(256) void gemm_dual0(
    const _Float16* __restrict__ A, int K,
    const _Float16* __restrict__ Wp,
    _Float16* __restrict__ ys, _Float16* __restrict__ yn)
{
    __shared__ _Float16 ldsA[3][4096];   // [kh(4)][128][8] per buf
    __shared__ _Float16 ldsB[3][4096];

    const int tid  = threadIdx.x;
    const int w    = tid >> 6;
    const int lane = tid & 63;

    const int wgid = xcd_swz(blockIdx.x, gridDim.x);
    const int bm   = (wgid >> 2) << 7;
    const int nb   = (wgid & 3) << 7;

    const int KT = K >> 5;   // 31

    auto stage = [&](int s, int kt) {
        const int k0 = kt << 5;
#pragma unroll
        for (int i = 0; i < 2; ++i) {
            const int j   = w + (i << 2);     // wave-uniform group 0..7
            const int c   = (j << 6) + lane;  // chunk: row=c&127, kh=c>>7
            const int row = c & 127;
            const int k8  = (c >> 7) << 3;
            gl2lds16(A  + (size_t)(bm + row) * K + k0 + k8, &ldsA[s][(size_t)j << 9]);
            gl2lds16(Wp + (size_t)(nb + row) * K + k0 + k8, &ldsB[s][(size_t)j << 9]);
        }
    };

    const int wm = (w >> 1) << 6;
    const int wn = (w & 1) << 6;
    const int lr = lane & 15;
    const int kh = lane >> 4;

    f32x4 acc[4][4] = {};

    stage(0, 0);
    stage(1, 1);
    int cur = 0;
    for (int kt = 0; kt < KT; ++kt) {
        if (kt + 1 < KT) PIPE_WAIT(4);   // step-kt loads landed; kt+1 (and kt+2 later) in flight
        else             PIPE_WAIT(0);
        SCHED_FENCE();
        __builtin_amdgcn_s_barrier();
        SCHED_FENCE();
        if (kt + 2 < KT) {
            const int s2 = (cur == 0) ? 2 : cur - 1;   // (cur+2)%3
            stage(s2, kt + 2);
        }
        f16x8 a[4], b[4];
#pragma unroll
        for (int mi = 0; mi < 4; ++mi)
            a[mi] = *(const f16x8*)&ldsA[cur][((kh << 7) + wm + (mi << 4) + lr) << 3];
#pragma unroll
        for (int ni = 0; ni < 4; ++ni)
            b[ni] = *(const f16x8*)&ldsB[cur][((kh << 7) + wn + (ni << 4) + lr) << 3];
#pragma unroll
        for (int mi = 0; mi < 4; ++mi)
#pragma unroll
            for (int ni = 0; ni < 4; ++ni)
                acc[mi][ni] = __builtin_amdgcn_mfma_f32_16x16x32_f16(a[mi], b[ni], acc[mi][ni], 0, 0, 0);
        cur = (cur == 2) ? 0 : cur + 1;
    }

    _Float16* C = (nb < 256) ? ys : yn;
    const int cb = (nb & 255) + wn;
#pragma unroll
    for (int mi = 0; mi < 4; ++mi) {
        const size_t rbase = (size_t)(bm + wm + (mi << 4) + (kh << 2)) << 8;
#pragma unroll
        for (int ni = 0; ni < 4; ++ni) {
            const int col = cb + (ni << 4) + lr;
#pragma unroll
            for (int r = 0; r < 4; ++r)
                C[rbase + ((size_t)r << 8) + col] = (_Float16)acc[mi][ni][r];
        }
    }
}

// ---------------- hidden GEMM, same 3-buffer pipeline: out = epi([X|AG] @ Wcat + b) --------
// Grid 1-D 782: wgid>>1 = row-tile, wgid&1 = col-block. K=512 (16 steps), A switches at kt=8.
template<int FINAL>
__global__ __launch_bounds__(256) void gemm_hidden(
    const _Float16* __restrict__ X, const _Float16* __restrict__ AG,
    const _Float16* __restrict__ Wp,        // [256 n][512 k]
    const float* __restrict__ bias,
    const _Float16* __restrict__ res,
    _Float16* __restrict__ outh, float* __restrict__ outf)
{
    __shared__ _Float16 ldsA[3][4096];
    __shared__ _Float16 ldsB[3][4096];

    const int tid  = threadIdx.x;
    const int w    = tid >> 6;
    const int lane = tid & 63;

    const int wgid = xcd_swz(blockIdx.x, gridDim.x);
    const int bm   = (wgid >> 1) << 7;
    const int nb   = (wgid & 1) << 7;      // 0 / 128

    auto stage = [&](int s, int kt) {
        const _Float16* Asrc = (kt < 8) ? X : AG;
        const int ka = (kt & 7) << 5;
#pragma unroll
        for (int i = 0; i < 2; ++i) {
            const int j   = w + (i << 2);
            const int c   = (j << 6) + lane;
            const int row = c & 127;
            const int k8  = (c >> 7) << 3;
            gl2lds16(Asrc + ((size_t)(bm + row) << 8) + ka + k8, &ldsA[s][(size_t)j << 9]);
            gl2lds16(Wp + (size_t)(nb + row) * 512 + (kt << 5) + k8, &ldsB[s][(size_t)j << 9]);
        }
    };

    const int wm = (w >> 1) << 6;
    const int wn = (w & 1) << 6;
    const int lr = lane & 15;
    const int kh = lane >> 4;

    f32x4 acc[4][4] = {};

    stage(0, 0);
    stage(1, 1);
    int cur = 0;
#pragma unroll
    for (int kt = 0; kt < 16; ++kt) {
        if (kt < 15) PIPE_WAIT(4);
        else         PIPE_WAIT(0);
        SCHED_FENCE();
        __builtin_amdgcn_s_barrier();
        SCHED_FENCE();
        if (kt + 2 < 16) {
            const int s2 = (cur == 0) ? 2 : cur - 1;
            stage(s2, kt + 2);
        }
        f16x8 a[4], b[4];
#pragma unroll
        for (int mi = 0; mi < 4; ++mi)
            a[mi] = *(const f16x8*)&ldsA[cur][((kh << 7) + wm + (mi << 4) + lr) << 3];
#pragma unroll
        for (int ni = 0; ni < 4; ++ni)
            b[ni] = *(const f16x8*)&ldsB[cur][((kh << 7) + wn + (ni << 4) + lr) << 3];
#pragma unroll
        for (int mi = 0; mi < 4; ++mi)
#pragma unroll
            for (int ni = 0; ni < 4; ++ni)
                acc[mi][ni] = __builtin_amdgcn_mfma_f32_16x16x32_f16(a[mi], b[ni], acc[mi][ni], 0, 0, 0);
        cur = (cur == 2) ? 0 : cur + 1;
    }

    // C/D: col = lane&15, row = (lane>>4)*4 + r  [m89/m91]
#pragma unroll
    for (int mi = 0; mi < 4; ++mi) {
        const int grow0 = bm + wm + (mi << 4) + (kh << 2);
#pragma unroll
        for (int ni = 0; ni < 4; ++ni) {
            const int col = nb + wn + (ni << 4) + lr;
            const float bcol = bias[col] * SCALE;
#pragma unroll
            for (int r = 0; r < 4; ++r) {
                const int grow = grow0 + r;
                float s = acc[mi][ni][r] + bcol;
                s = fmaxf(s, 0.f);
                if (res) s = ((float)res[((size_t)grow << 8) + col] + s) * 0.5f;
                if (FINAL) {
                    if (grow < NNODES) outf[((size_t)grow << 8) + col] = s * ISCALE;
                } else {
                    outh[((size_t)grow << 8) + col] = (_Float16)s;
                }
            }
        }
    }
}

// ------------- gather16: agg[r][c8..) = sum_j X[nbr[r][j]][c8..)  (fp16 pairwise tree) -----
__global__ __launch_bounds__(256) void gather16(
    const _Float16* __restrict__ X, const int* __restrict__ nbr,
    _Float16* __restrict__ agg)
{
    const int idx = blockIdx.x * 256 + threadIdx.x;   // NPAD * 32
    const int r   = idx >> 5;
    const int c8  = (idx & 31) << 3;
    const int rr  = (r < NNODES) ? r : (NNODES - 1);
    const int4* np = (const int4*)(nbr + rr * DEG);
    const int4 q0 = np[0], q1 = np[1], q2 = np[2], q3 = np[3];

    f16x8 v[16];
#define LD16(slot, n) v[slot] = *(const f16x8*)(X + ((size_t)(n) << 8) + c8)
    LD16(0,  q0.x); LD16(1,  q0.y); LD16(2,  q0.z); LD16(3,  q0.w);
    LD16(4,  q1.x); LD16(5,  q1.y); LD16(6,  q1.z); LD16(7,  q1.w);
    LD16(8,  q2.x); LD16(9,  q2.y); LD16(10, q2.z); LD16(11, q2.w);
    LD16(12, q3.x); LD16(13, q3.y); LD16(14, q3.z); LD16(15, q3.w);
#undef LD16
    const f16x8 s0 = ((v[0] + v[1]) + (v[2] + v[3])) + ((v[4] + v[5]) + (v[6] + v[7]));
    const f16x8 s1 = ((v[8] + v[9]) + (v[10] + v[11])) + ((v[12] + v[13]) + (v[14] + v[15]));
    const f16x8 o  = s0 + s1;
    *(f16x8*)(agg + ((size_t)r << 8) + c8) = o;
}

// ------------- layer-0 combine (fp32 accum): P = relu(ys + gather(yn) + b0*SCALE) ---------
__global__ __launch_bounds__(256) void combine16(
    const _Float16* __restrict__ ys, const _Float16* __restrict__ yn,
    const int* __restrict__ nbr, const float* __restrict__ bias,
    _Float16* __restrict__ outh)
{
    const int idx = blockIdx.x * 256 + threadIdx.x;   // NNODES * 32
    const int r   = idx >> 5;
    const int c8  = (idx & 31) << 3;
    const int4* np = (const int4*)(nbr + r * DEG);
    const int4 q0 = np[0], q1 = np[1], q2 = np[2], q3 = np[3];

    f16x8 v[16];
#define LD16(slot, n) v[slot] = *(const f16x8*)(yn + ((size_t)(n) << 8) + c8)
    LD16(0,  q0.x); LD16(1,  q0.y); LD16(2,  q0.z); LD16(3,  q0.w);
    LD16(4,  q1.x); LD16(5,  q1.y); LD16(6,  q1.z); LD16(7,  q1.w);
    LD16(8,  q2.x); LD16(9,  q2.y); LD16(10, q2.z); LD16(11, q2.w);
    LD16(12, q3.x); LD16(13, q3.y); LD16(14, q3.z); LD16(15, q3.w);
#undef LD16
    const f16x8 ysv = *(const f16x8*)(ys + ((size_t)r << 8) + c8);
    const float4 b0 = *(const float4*)(bias + c8);
    const float4 b1 = *(const float4*)(bias + c8 + 4);
    const float bb[8] = {b0.x, b0.y, b0.z, b0.w, b1.x, b1.y, b1.z, b1.w};
    f16x8 o;
#pragma unroll
    for (int i = 0; i < 8; ++i) {
        float s = (float)ysv[i] + bb[i] * SCALE;
#pragma unroll
        for (int j = 0; j < 16; ++j) s += (float)v[j][i];
        o[i] = (_Float16)fmaxf(s, 0.f);
    }
    *(f16x8*)(outh + ((size_t)r << 8) + c8) = o;
}

// ------------- coords head -------------
__global__ __launch_bounds__(64) void coords_kernel(
    const float* __restrict__ x, const float* __restrict__ We,
    const float* __restrict__ be, float* __restrict__ out3, int N)
{
    const int n = blockIdx.x;
    const int l = threadIdx.x;
    const float4 xv = *(const float4*)(x + (size_t)n * 256 + l * 4);
    float p0 = 0.f, p1 = 0.f, p2 = 0.f;
    const float xs[4] = {xv.x, xv.y, xv.z, xv.w};
#pragma unroll
    for (int i = 0; i < 4; ++i) {
        const int cidx = l * 4 + i;
        p0 += xs[i] * We[cidx * 3 + 0];
        p1 += xs[i] * We[cidx * 3 + 1];
        p2 += xs[i] * We[cidx * 3 + 2];
    }
#pragma unroll
    for (int off = 32; off > 0; off >>= 1) {
        p0 += __shfl_down(p0, off);
        p1 += __shfl_down(p1, off);
        p2 += __shfl_down(p2, off);
    }
    if (l == 0) {
        out3[(size_t)n * 3 + 0] = p0 + be[0];
        out3[(size_t)n * 3 + 1] = p1 + be[1];
        out3[(size_t)n * 3 + 2] = p2 + be[2];
    }
}

// ------------- conversion / packing kernels -------------
__global__ __launch_bounds__(256) void conv_sf(const float* __restrict__ sf,
                                               _Float16* __restrict__ sfb)
{
    const int idx = blockIdx.x * 256 + threadIdx.x;   // NPAD * 124
    const int row = idx / 124;
    const int k8  = (idx % 124) << 3;
    f16x8 o = {};
    if (row < NNODES) {
#pragma unroll
        for (int i = 0; i < 8; ++i) {
            const int k = k8 + i;
            o[i] = (k < DIN) ? (_Float16)(sf[(size_t)row * DIN + k] * SCALE) : (_Float16)0.f;
        }
    }
    *(f16x8*)(sfb + (size_t)row * K0PAD + k8) = o;
}

__global__ __launch_bounds__(256) void pack_w0(const float* __restrict__ Ws0,
                                               const float* __restrict__ Wn0,
                                               _Float16* __restrict__ Wp0)
{
    const int idx = blockIdx.x * 256 + threadIdx.x;   // 512 * 124
    const int nn  = idx & 511;
    const int k8  = idx >> 9;
    const float* W = (nn < 256) ? Ws0 : Wn0;
    const int n0 = nn & 255;
    f16x8 o;
#pragma unroll
    for (int i = 0; i < 8; ++i) {
        const int k = (k8 << 3) + i;
        o[i] = (k < DIN) ? (_Float16)W[(size_t)k * 256 + n0] : (_Float16)0.f;
    }
    *(f16x8*)(Wp0 + (size_t)nn * K0PAD + (k8 << 3)) = o;
}

__global__ __launch_bounds__(256) void pack_w2(const float* __restrict__ Ws,
                                               const float* __restrict__ Wn,
                                               _Float16* __restrict__ Wpk2)
{
    const int idx = blockIdx.x * 256 + threadIdx.x;   // 13 * 64 * 256
    const int n   = idx & 255;
    const int k8  = (idx >> 8) & 63;
    const int l   = idx >> 14;
    f16x8 o;
#pragma unroll
    for (int i = 0; i < 8; ++i) {
        const int k = (k8 << 3) + i;
        const float* W = (k < 256) ? Ws : Wn;
        o[i] = (_Float16)W[(size_t)l * 65536 + (k & 255) * 256 + n];
    }
    *(f16x8*)(Wpk2 + (size_t)l * 131072 + (size_t)n * 512 + (k8 << 3)) = o;
}

extern "C" void kernel_launch(void* const* d_in, const int* in_sizes, int n_in,
                              void* d_out, int out_size, void* d_ws, size_t ws_size,
                              hipStream_t stream)
{
    const int*   nbr = (const int*)d_in[0];
    const float* sf  = (const float*)d_in[1];
    const float* Ws0 = (const float*)d_in[2];
    const float* Wn0 = (const float*)d_in[3];
    const float* b0  = (const float*)d_in[4];
    const float* Ws  = (const float*)d_in[5];
    const float* Wn  = (const float*)d_in[6];
    const float* bb  = (const float*)d_in[7];
    const float* We  = (const float*)d_in[8];
    const float* be  = (const float*)d_in[9];
    float* out = (float*)d_out;

    uint8_t* w = (uint8_t*)d_ws;
    _Float16* sfb  = (_Float16*)w;
    _Float16* P    = (_Float16*)w;
    _Float16* Q    = P + (size_t)NPAD * 256;
    _Float16* R    = Q + (size_t)NPAD * 256;
    _Float16* Wpk2 = R + (size_t)NPAD * 256;
    _Float16* Wp0  = (_Float16*)(w + (size_t)NPAD * K0PAD * 2);
    _Float16* ysb  = Wp0 + (size_t)512 * K0PAD;
    _Float16* ynb  = ysb + (size_t)NPAD * 256;
    _Float16* agg  = ysb;

    conv_sf<<<NPAD * 124 / 256, 256, 0, stream>>>(sf, sfb);
    pack_w0<<<512 * 124 / 256, 256, 0, stream>>>(Ws0, Wn0, Wp0);

    gemm_dual0<<<(NPAD / 128) * 4, 256, 0, stream>>>(sfb, K0PAD, Wp0, ysb, ynb);
    pack_w2<<<13 * 64 * 256 / 256, 256, 0, stream>>>(Ws, Wn, Wpk2);
    combine16<<<NNODES * 32 / 256, 256, 0, stream>>>(ysb, ynb, nbr, b0, P);

    const int hg = (NPAD / 128) * 2;   // 782
    const int gg = NPAD * 32 / 256;    // 6256

    _Float16* buf[3] = {P, Q, R};
    int xi = 0;
    for (int t = 0; t < 6; ++t) {
        const int lA = 2 * t, lB = lA + 1;
        _Float16* a = buf[(xi + 1) % 3];
        _Float16* b = buf[(xi + 2) % 3];
        gather16<<<gg, 256, 0, stream>>>(buf[xi], nbr, agg);
        gemm_hidden<0><<<hg, 256, 0, stream>>>(buf[xi], agg, Wpk2 + (size_t)lA * 131072,
                                               bb + lA * 256, nullptr, a, nullptr);
        gather16<<<gg, 256, 0, stream>>>(a, nbr, agg);
        gemm_hidden<0><<<hg, 256, 0, stream>>>(a, agg, Wpk2 + (size_t)lB * 131072,
                                               bb + lB * 256, buf[xi], b, nullptr);
        xi = (xi + 2) % 3;
    }

    gather16<<<gg, 256, 0, stream>>>(buf[xi], nbr, agg);
    gemm_hidden<1><<<hg, 256, 0, stream>>>(buf[xi], agg, Wpk2 + (size_t)12 * 131072,
                                           bb + 12 * 256, nullptr, nullptr, out);

    coords_kernel<<<NNODES, 64, 0, stream>>>(out, We, be, out + (size_t)NNODES * 256, NNODES);
}

// Round 12
// 1546.300 us; speedup vs baseline: 1.1045x; 1.1045x over previous
//
#include <hip/hip_runtime.h>
#include <hip/hip_bf16.h>
#include <hip/hip_fp16.h>
#include <stdint.h>

#define NNODES 50000
#define NPAD   50048          // 391 * 128
#define DEG    16
#define DIN    963
#define K0PAD  992            // 31 * 32
#define DHID   256
#define SCALE  (1.0f / 1024.0f)
#define ISCALE 1024.0f

typedef __attribute__((ext_vector_type(4))) float    f32x4;
typedef __attribute__((ext_vector_type(8))) _Float16 f16x8;
typedef __attribute__((ext_vector_type(4))) _Float16 f16x4;

typedef const __attribute__((address_space(1))) void GV;
typedef __attribute__((address_space(3))) void LV;

__device__ __forceinline__ void gl2lds16(const void* g, void* l) {
    __builtin_amdgcn_global_load_lds((GV*)g, (LV*)l, 16, 0, 0);
}

// bijective XCD swizzle (m204)
__device__ __forceinline__ int xcd_swz(int bid, int nwg) {
    const int q = nwg >> 3, r_ = nwg & 7, xc = bid & 7;
    return (xc < r_ ? xc * (q + 1) : r_ * (q + 1) + (xc - r_) * q) + (bid >> 3);
}

// ---------------- layer-0 dual GEMM ----------------
// R2 structure + R10 grid (1-D, col-siblings adjacent -> A-tile L2 share) +
// swapped-operand epilogue: mfma(b,a,acc) gives lane 4 consecutive C-COLUMNS
// per acc reg -> f16x4 8B stores (16 instrs) instead of 64 scalar 2B stores.
__global__ __launch_bounds__(256) void gemm_dual0(
    const _Float16* __restrict__ A, int K,
    const _Float16* __restrict__ Wp,
    _Float16* __restrict__ ys, _Float16* __restrict__ yn)
{
    __shared__ _Float16 lds[2][2][4096];   // [buf][A/B][kh(4)][128][8]

    const int tid  = threadIdx.x;
    const int w    = tid >> 6;
    const int lane = tid & 63;

    const int wgid = xcd_swz(blockIdx.x, gridDim.x);
    const int bm   = (wgid >> 2) << 7;
    const int nb   = (wgid & 3) << 7;

    const int KT = K >> 5;

    auto stage = [&](int s, int kt) {
        const int k0 = kt << 5;
#pragma unroll
        for (int i = 0; i < 2; ++i) {
            const int j   = w + (i << 2);
            const int c   = (j << 6) + lane;
            const int row = c & 127;
            const int k8  = (c >> 7) << 3;
            gl2lds16(A  + (size_t)(bm + row) * K + k0 + k8, &lds[s][0][(size_t)j << 9]);
            gl2lds16(Wp + (size_t)(nb + row) * K + k0 + k8, &lds[s][1][(size_t)j << 9]);
        }
    };

    const int wm = (w >> 1) << 6;
    const int wn = (w & 1) << 6;
    const int lr = lane & 15;
    const int kh = lane >> 4;

    f32x4 acc[4][4] = {};

    stage(0, 0);
    __syncthreads();
    int cur = 0;
    for (int kt = 0; kt < KT; ++kt) {
        if (kt + 1 < KT) stage(cur ^ 1, kt + 1);
        f16x8 a[4], b[4];
#pragma unroll
        for (int mi = 0; mi < 4; ++mi)
            a[mi] = *(const f16x8*)&lds[cur][0][((kh << 7) + wm + (mi << 4) + lr) << 3];
#pragma unroll
        for (int ni = 0; ni < 4; ++ni)
            b[ni] = *(const f16x8*)&lds[cur][1][((kh << 7) + wn + (ni << 4) + lr) << 3];
#pragma unroll
        for (int mi = 0; mi < 4; ++mi)
#pragma unroll
            for (int ni = 0; ni < 4; ++ni)
                acc[mi][ni] = __builtin_amdgcn_mfma_f32_16x16x32_f16(b[ni], a[mi], acc[mi][ni], 0, 0, 0);
        __syncthreads();
        cur ^= 1;
    }

    // Swapped C/D: lane holds C[m = ...+lr][col0 + r], r = 0..3. [m89/m91 transposed]
    _Float16* C = (nb < 256) ? ys : yn;
    const int cb = (nb & 255) + wn;
#pragma unroll
    for (int mi = 0; mi < 4; ++mi) {
        const int m = bm + wm + (mi << 4) + lr;
#pragma unroll
        for (int ni = 0; ni < 4; ++ni) {
            const int col0 = cb + (ni << 4) + (kh << 2);
            f16x4 o;
#pragma unroll
            for (int r = 0; r < 4; ++r) o[r] = (_Float16)acc[mi][ni][r];
            *(f16x4*)(C + ((size_t)m << 8) + col0) = o;
        }
    }
}

// ---------------- fused hidden layer (R7 v3 + swapped epilogue) --------------
// 128(M) x 256(N), 512 thr = 8 waves (2M x 4N), A/B via global_load_lds,
// double-buffered [kh][row][8] LDS. Gather for step kt+1 split: first 8 nbr
// loads before MFMA(kt), sum + second 8 + ds_write after.
template<int FINAL>
__global__ __launch_bounds__(512) void fused_layer(
    const _Float16* __restrict__ X, const int* __restrict__ nbr,
    const _Float16* __restrict__ W, const float* __restrict__ bias,
    const _Float16* __restrict__ res,
    _Float16* __restrict__ outh, float* __restrict__ outf)
{
    __shared__ _Float16 ldsA[2][4096];   // [kh(4)][128][8]  = 8KB/buf
    __shared__ _Float16 ldsB[2][8192];   // [kh(4)][256][8]  = 16KB/buf

    const int tid  = threadIdx.x;
    const int w    = tid >> 6;
    const int lane = tid & 63;
    const int bm   = blockIdx.x << 7;

    // gather role: 4 threads per row, each owns an 8-k slice of the 32-k window
    const int growg = bm + (tid >> 2);
    const int nrow  = (growg < NNODES) ? growg : (NNODES - 1);
    const int4* np  = (const int4*)(nbr + nrow * DEG);
    const int4 q0 = np[0], q1 = np[1], q2 = np[2], q3 = np[3];
    const int kq = (tid & 3) << 3;

    auto GLD = [&](int r, int ko) -> f16x8 {
        return *(const f16x8*)(X + ((size_t)r << 8) + ko);
    };
    auto stageAself = [&](int s, int kt) {
        const int c = tid;      // chunk: row=c&127, kh=c>>7
        gl2lds16(X + ((size_t)(bm + (c & 127)) << 8) + (kt << 5) + ((c >> 7) << 3),
                 &ldsA[s][(size_t)c << 3]);
    };
    auto stageB = [&](int s, int kt) {
#pragma unroll
        for (int i = 0; i < 2; ++i) {   // 1024 chunks; chunk c: n=c&255, kh=c>>8
            const int c = (i << 9) + tid;
            gl2lds16(W + ((size_t)(c & 255) << 9) + (kt << 5) + ((c >> 8) << 3),
                     &ldsB[s][(size_t)c << 3]);
        }
    };

    const int wm = (w >> 2) << 6;   // 0/64
    const int wn = (w & 3) << 6;    // 0/64/128/192
    const int lr = lane & 15;
    const int kh = lane >> 4;

    f32x4 acc[4][4] = {};
    f16x8 g0, g1, g2, g3, g4, g5, g6, g7;

    stageAself(0, 0);
    stageB(0, 0);
    __syncthreads();

    int cur = 0;
#pragma unroll
    for (int kt = 0; kt < 16; ++kt) {
        const int nxt = kt + 1;
        if (nxt < 16) {
            if (nxt < 8) {
                stageAself(cur ^ 1, nxt);
            } else {   // issue first 8 gather loads for step nxt (hidden under MFMA)
                const int ko = ((nxt - 8) << 5) + kq;
                g0 = GLD(q0.x, ko); g1 = GLD(q0.y, ko); g2 = GLD(q0.z, ko); g3 = GLD(q0.w, ko);
                g4 = GLD(q1.x, ko); g5 = GLD(q1.y, ko); g6 = GLD(q1.z, ko); g7 = GLD(q1.w, ko);
            }
            stageB(cur ^ 1, nxt);
        }
        f16x8 a[4], b[4];
#pragma unroll
        for (int mi = 0; mi < 4; ++mi)
            a[mi] = *(const f16x8*)&ldsA[cur][((kh << 7) + wm + (mi << 4) + lr) << 3];
#pragma unroll
        for (int ni = 0; ni < 4; ++ni)
            b[ni] = *(const f16x8*)&ldsB[cur][((kh << 8) + wn + (ni << 4) + lr) << 3];
#pragma unroll
        for (int mi = 0; mi < 4; ++mi)
#pragma unroll
            for (int ni = 0; ni < 4; ++ni)
                acc[mi][ni] = __builtin_amdgcn_mfma_f32_16x16x32_f16(b[ni], a[mi], acc[mi][ni], 0, 0, 0);
        if (nxt >= 8 && nxt < 16) {
            const int ko = ((nxt - 8) << 5) + kq;
            f16x8 s0 = ((g0 + g1) + (g2 + g3)) + ((g4 + g5) + (g6 + g7));
            g0 = GLD(q2.x, ko); g1 = GLD(q2.y, ko); g2 = GLD(q2.z, ko); g3 = GLD(q2.w, ko);
            g4 = GLD(q3.x, ko); g5 = GLD(q3.y, ko); g6 = GLD(q3.z, ko); g7 = GLD(q3.w, ko);
            f16x8 s1 = ((g0 + g1) + (g2 + g3)) + ((g4 + g5) + (g6 + g7));
            *(f16x8*)&ldsA[cur ^ 1][(size_t)(((tid & 3) << 7) + (tid >> 2)) << 3] = s0 + s1;
        }
        __syncthreads();
        cur ^= 1;
    }

    // Swapped epilogue: lane holds C[m][col0 + r], r = 0..3 (4 consecutive cols).
#pragma unroll
    for (int mi = 0; mi < 4; ++mi) {
        const int m = bm + wm + (mi << 4) + lr;
        const size_t mb = (size_t)m << 8;
#pragma unroll
        for (int ni = 0; ni < 4; ++ni) {
            const int col0 = wn + (ni << 4) + (kh << 2);
            const float4 bv = *(const float4*)(bias + col0);
            float s0 = fmaxf(acc[mi][ni][0] + bv.x * SCALE, 0.f);
            float s1 = fmaxf(acc[mi][ni][1] + bv.y * SCALE, 0.f);
            float s2 = fmaxf(acc[mi][ni][2] + bv.z * SCALE, 0.f);
            float s3 = fmaxf(acc[mi][ni][3] + bv.w * SCALE, 0.f);
            if (res) {
                const f16x4 rv = *(const f16x4*)(res + mb + col0);
                s0 = ((float)rv[0] + s0) * 0.5f;
                s1 = ((float)rv[1] + s1) * 0.5f;
                s2 = ((float)rv[2] + s2) * 0.5f;
                s3 = ((float)rv[3] + s3) * 0.5f;
            }
            if (FINAL) {
                if (m < NNODES) {
                    float4 o = make_float4(s0 * ISCALE, s1 * ISCALE, s2 * ISCALE, s3 * ISCALE);
                    *(float4*)(outf + mb + col0) = o;
                }
            } else {
                f16x4 o;
                o[0] = (_Float16)s0; o[1] = (_Float16)s1;
                o[2] = (_Float16)s2; o[3] = (_Float16)s3;
                *(f16x4*)(outh + mb + col0) = o;
            }
        }
    }
}

// ------------- layer-0 combine (16B requests, fp32 accum) -------------
__global__ __launch_bounds__(256) void combine16(
    const _Float16* __restrict__ ys, const _Float16* __restrict__ yn,
    const int* __restrict__ nbr, const float* __restrict__ bias,
    _Float16* __restrict__ outh)
{
    const int idx = blockIdx.x * 256 + threadIdx.x;   // NNODES * 32
    const int r   = idx >> 5;
    const int c8  = (idx & 31) << 3;
    const int4* np = (const int4*)(nbr + r * DEG);
    const int4 q0 = np[0], q1 = np[1], q2 = np[2], q3 = np[3];

    f16x8 v[16];
#define LD16(slot, n) v[slot] = *(const f16x8*)(yn + ((size_t)(n) << 8) + c8)
    LD16(0,  q0.x); LD16(1,  q0.y); LD16(2,  q0.z); LD16(3,  q0.w);
    LD16(4,  q1.x); LD16(5,  q1.y); LD16(6,  q1.z); LD16(7,  q1.w);
    LD16(8,  q2.x); LD16(9,  q2.y); LD16(10, q2.z); LD16(11, q2.w);
    LD16(12, q3.x); LD16(13, q3.y); LD16(14, q3.z); LD16(15, q3.w);
#undef LD16
    const f16x8 ysv = *(const f16x8*)(ys + ((size_t)r << 8) + c8);
    const float4 b0 = *(const float4*)(bias + c8);
    const float4 b1 = *(const float4*)(bias + c8 + 4);
    const float bb[8] = {b0.x, b0.y, b0.z, b0.w, b1.x, b1.y, b1.z, b1.w};
    f16x8 o;
#pragma unroll
    for (int i = 0; i < 8; ++i) {
        float s = (float)ysv[i] + bb[i] * SCALE;
#pragma unroll
        for (int j = 0; j < 16; ++j) s += (float)v[j][i];
        o[i] = (_Float16)fmaxf(s, 0.f);
    }
    *(f16x8*)(outh + ((size_t)r << 8) + c8) = o;
}

// ------------- coords head: out3 = x @ We (256x3) + be (fp32, unscaled) -------------
__global__ __launch_bounds__(64) void coords_kernel(
    const float* __restrict__ x, const float* __restrict__ We,
    const float* __restrict__ be, float* __restrict__ out3, int N)
{
    const int n = blockIdx.x;
    const int l = threadIdx.x;
    const float4 xv = *(const float4*)(x + (size_t)n * 256 + l * 4);
    float p0 = 0.f, p1 = 0.f, p2 = 0.f;
    const float xs[4] = {xv.x, xv.y, xv.z, xv.w};
#pragma unroll
    for (int i = 0; i < 4; ++i) {
        const int cidx = l * 4 + i;
        p0 += xs[i] * We[cidx * 3 + 0];
        p1 += xs[i] * We[cidx * 3 + 1];
        p2 += xs[i] * We[cidx * 3 + 2];
    }
#pragma unroll
    for (int off = 32; off > 0; off >>= 1) {
        p0 += __shfl_down(p0, off);
        p1 += __shfl_down(p1, off);
        p2 += __shfl_down(p2, off);
    }
    if (l == 0) {
        out3[(size_t)n * 3 + 0] = p0 + be[0];
        out3[(size_t)n * 3 + 1] = p1 + be[1];
        out3[(size_t)n * 3 + 2] = p2 + be[2];
    }
}

// ------------- conversion / packing kernels -------------
__global__ __launch_bounds__(256) void conv_sf(const float* __restrict__ sf,
                                               _Float16* __restrict__ sfb)
{
    const int idx = blockIdx.x * 256 + threadIdx.x;   // NPAD * 124
    const int row = idx / 124;
    const int k8  = (idx % 124) << 3;
    f16x8 o = {};
    if (row < NNODES) {
#pragma unroll
        for (int i = 0; i < 8; ++i) {
            const int k = k8 + i;
            o[i] = (k < DIN) ? (_Float16)(sf[(size_t)row * DIN + k] * SCALE) : (_Float16)0.f;
        }
    }
    *(f16x8*)(sfb + (size_t)row * K0PAD + k8) = o;
}

__global__ __launch_bounds__(256) void pack_w0(const float* __restrict__ Ws0,
                                               const float* __restrict__ Wn0,
                                               _Float16* __restrict__ Wp0)
{
    const int idx = blockIdx.x * 256 + threadIdx.x;   // 512 * 124
    const int nn  = idx & 511;
    const int k8  = idx >> 9;
    const float* W = (nn < 256) ? Ws0 : Wn0;
    const int n0 = nn & 255;
    f16x8 o;
#pragma unroll
    for (int i = 0; i < 8; ++i) {
        const int k = (k8 << 3) + i;
        o[i] = (k < DIN) ? (_Float16)W[(size_t)k * 256 + n0] : (_Float16)0.f;
    }
    *(f16x8*)(Wp0 + (size_t)nn * K0PAD + (k8 << 3)) = o;
}

// Ws/Wn [13][256][256] f32 -> Wpk2 [13][256(n)][512(k)] fp16: Wpk2[l][n][k] = Wcat[k][n]
__global__ __launch_bounds__(256) void pack_w2(const float* __restrict__ Ws,
                                               const float* __restrict__ Wn,
                                               _Float16* __restrict__ Wpk2)
{
    const int idx = blockIdx.x * 256 + threadIdx.x;   // 13 * 64 * 256
    const int n   = idx & 255;
    const int k8  = (idx >> 8) & 63;
    const int l   = idx >> 14;
    f16x8 o;
#pragma unroll
    for (int i = 0; i < 8; ++i) {
        const int k = (k8 << 3) + i;
        const float* W = (k < 256) ? Ws : Wn;
        o[i] = (_Float16)W[(size_t)l * 65536 + (k & 255) * 256 + n];
    }
    *(f16x8*)(Wpk2 + (size_t)l * 131072 + (size_t)n * 512 + (k8 << 3)) = o;
}

extern "C" void kernel_launch(void* const* d_in, const int* in_sizes, int n_in,
                              void* d_out, int out_size, void* d_ws, size_t ws_size,
                              hipStream_t stream)
{
    const int*   nbr = (const int*)d_in[0];
    const float* sf  = (const float*)d_in[1];
    const float* Ws0 = (const float*)d_in[2];
    const float* Wn0 = (const float*)d_in[3];
    const float* b0  = (const float*)d_in[4];
    const float* Ws  = (const float*)d_in[5];
    const float* Wn  = (const float*)d_in[6];
    const float* bb  = (const float*)d_in[7];
    const float* We  = (const float*)d_in[8];
    const float* be  = (const float*)d_in[9];
    float* out = (float*)d_out;

    // Workspace (151.6 MB):
    //   [0, 99.3MB)   : sfb [NPAD][992] fp16 -- consumed by layer-0 GEMM, then reused:
    //                     P = +0, Q = +25.6MB, Wpk2 = +51.2MB (packed AFTER layer-0 GEMM)
    //   [99.3,100.3)  : Wp0 [512][992] fp16
    //   [100.3,125.9) : ysb [NPAD][256] fp16
    //   [125.9,151.6) : ynb [NPAD][256] fp16
    uint8_t* w = (uint8_t*)d_ws;
    _Float16* sfb  = (_Float16*)w;
    _Float16* P    = (_Float16*)w;
    _Float16* Q    = P + (size_t)NPAD * 256;
    _Float16* Wpk2 = Q + (size_t)NPAD * 256;
    _Float16* Wp0  = (_Float16*)(w + (size_t)NPAD * K0PAD * 2);
    _Float16* ysb  = Wp0 + (size_t)512 * K0PAD;
    _Float16* ynb  = ysb + (size_t)NPAD * 256;

    conv_sf<<<NPAD * 124 / 256, 256, 0, stream>>>(sf, sfb);
    pack_w0<<<512 * 124 / 256, 256, 0, stream>>>(Ws0, Wn0, Wp0);

    // Layer 0 (K=992): 1-D grid, col-siblings adjacent + XCD swizzle.
    gemm_dual0<<<(NPAD / 128) * 4, 256, 0, stream>>>(sfb, K0PAD, Wp0, ysb, ynb);
    pack_w2<<<13 * 64 * 256 / 256, 256, 0, stream>>>(Ws, Wn, Wpk2);
    combine16<<<NNODES * 32 / 256, 256, 0, stream>>>(ysb, ynb, nbr, b0, P);

    const int fg = NPAD / 128;   // 391

    for (int t = 0; t < 6; ++t) {
        const int lA = 2 * t, lB = lA + 1;
        fused_layer<0><<<fg, 512, 0, stream>>>(P, nbr, Wpk2 + (size_t)lA * 131072,
                                               bb + lA * 256, nullptr, Q, nullptr);
        fused_layer<0><<<fg, 512, 0, stream>>>(Q, nbr, Wpk2 + (size_t)lB * 131072,
                                               bb + lB * 256, P, P, nullptr);
    }

    fused_layer<1><<<fg, 512, 0, stream>>>(P, nbr, Wpk2 + (size_t)12 * 131072,
                                           bb + 12 * 256, nullptr, nullptr, out);

    coords_kernel<<<NNODES, 64, 0, stream>>>(out, We, be, out + (size_t)NNODES * 256, NNODES);
}